// Round 5
// baseline (1336.397 us; speedup 1.0000x reference)
//
#include <hip/hip_runtime.h>
#include <hip/hip_bf16.h>
#include <math.h>

#define SQH 0.70710678118654752440f

typedef __bf16 bf16x8 __attribute__((ext_vector_type(8)));
typedef float f32x4 __attribute__((ext_vector_type(4)));

__device__ __forceinline__ void glds16(const void* g, void* l) {
    __builtin_amdgcn_global_load_lds((const __attribute__((address_space(1))) void*)g,
                                     (__attribute__((address_space(3))) void*)l, 16, 0, 0);
}

// bijective XCD swizzle (requires n % 8 == 0): contiguous logical chunk per XCD
__device__ __forceinline__ int xcd_swz(int lin, int n) {
    if (n & 7) return lin;
    return (lin & 7) * (n >> 3) + (lin >> 3);
}

// ---------------- positional encoding table ----------------
__global__ void pos_enc_kernel(float* __restrict__ pe, int T, float rate) {
    int idx = blockIdx.x * blockDim.x + threadIdx.x;
    if (idx >= T * 256) return;
    int t = idx >> 8;
    int k = idx & 255;
    float e = 2.0f * (float)(k >> 1) / 256.0f;
    float pw = powf(10000.0f, e);
    float ang = (float)t * ((float)t * rate / pw);
    pe[idx] = ((k & 1) == 0) ? sinf(ang) : cosf(ang);
}

__global__ void zero_init(float* z) { z[threadIdx.x] = 0.f; }

// ---------------- f32 -> bf16 convert (groups of 8) ----------------
__global__ __launch_bounds__(256) void cvt_bf(const float* __restrict__ src,
                                              __bf16* __restrict__ dst, long n8) {
    long i = (long)blockIdx.x * 256 + threadIdx.x;
    if (i >= n8) return;
    const float* s = src + i * 8;
    float4 a = *(const float4*)s, b = *(const float4*)(s + 4);
    bf16x8 o;
    o[0] = (__bf16)a.x; o[1] = (__bf16)a.y; o[2] = (__bf16)a.z; o[3] = (__bf16)a.w;
    o[4] = (__bf16)b.x; o[5] = (__bf16)b.y; o[6] = (__bf16)b.z; o[7] = (__bf16)b.w;
    *(bf16x8*)(dst + i * 8) = o;
}

// ---------------- keys + pek -> bf16 ----------------
__global__ __launch_bounds__(256) void kpe_kernel(const float* __restrict__ keys,
                                                  const float* __restrict__ pek,
                                                  __bf16* __restrict__ dst) {
    long i = (long)blockIdx.x * 256 + threadIdx.x;
    long row = i >> 5; int c8 = (int)(i & 31) << 3;
    const float* kp = keys + row * 256 + c8;
    const float* pp = pek + (row & 511) * 256 + c8;
    float4 a = *(const float4*)kp, b = *(const float4*)(kp + 4);
    float4 p = *(const float4*)pp, q = *(const float4*)(pp + 4);
    bf16x8 o;
    o[0] = (__bf16)(a.x + p.x); o[1] = (__bf16)(a.y + p.y);
    o[2] = (__bf16)(a.z + p.z); o[3] = (__bf16)(a.w + p.w);
    o[4] = (__bf16)(b.x + q.x); o[5] = (__bf16)(b.y + q.y);
    o[6] = (__bf16)(b.z + q.z); o[7] = (__bf16)(b.w + q.w);
    *(bf16x8*)(dst + i * 8) = o;
}

// ---------------- weight transpose: src[R][C] f32 -> dst[C][R] bf16 ----------------
__global__ __launch_bounds__(256) void transpose_k(const float* __restrict__ src,
                                                   __bf16* __restrict__ dst,
                                                   int R, int Cc, long sS, long sD) {
    __shared__ float tile[32][33];
    src += (long)blockIdx.z * sS;
    dst += (long)blockIdx.z * sD;
    int c0 = blockIdx.x * 32, r0 = blockIdx.y * 32;
    int tx = threadIdx.x & 31, ty = threadIdx.x >> 5;
#pragma unroll
    for (int p = 0; p < 4; ++p)
        tile[ty + 8 * p][tx] = src[(long)(r0 + ty + 8 * p) * Cc + c0 + tx];
    __syncthreads();
#pragma unroll
    for (int p = 0; p < 4; ++p)
        dst[(long)(c0 + ty + 8 * p) * R + r0 + tx] = (__bf16)tile[tx][ty + 8 * p];
}

// ---------------- universal bf16 MFMA GEMM (global_load_lds staging, XCD swz) ----------------
// C = epi(A[M,K] @ Bt[N,K]^T + bias). BIAS_MODE: 0 none, 1 col, 2 row.
// ACT: 0 none, 1 relu. OUT_MODE: 0 f32, 1 bf16, 2 both. RES: 1 -> v=(v+res)*SQH.
template<int BIAS_MODE, int ACT, int OUT_MODE, int RES>
__global__ __launch_bounds__(256) void gemm_bf(
    const __bf16* __restrict__ A, const __bf16* __restrict__ Bt,
    const float* __restrict__ bias, const float* __restrict__ res,
    float* __restrict__ outF, __bf16* __restrict__ outB,
    int M, int N, int K, long sA, long sB, long sC)
{
    __shared__ __align__(16) __bf16 As[4096];
    __shared__ __align__(16) __bf16 Bs[4096];
    const int gx = gridDim.x, gy = gridDim.y;
    int lin = (blockIdx.z * gy + blockIdx.y) * gx + blockIdx.x;
    lin = xcd_swz(lin, gx * gy * gridDim.z);
    const int bx = lin % gx, by = (lin / gx) % gy, z = lin / (gx * gy);
    A += (long)z * sA;
    Bt += (long)z * sB;
    const int row0 = by << 7, col0 = bx << 7;
    const int tid = threadIdx.x, wid = tid >> 6, lane = tid & 63;
    const int lrow = lane & 15, lkp = lane >> 4;
    const int wm = (wid >> 1) << 6, wn = (wid & 1) << 6;
    const int srow = (wid << 5) + (lane >> 2);
    const int kq8 = (lane & 3) << 3;
    const __bf16* Ap0 = A + (long)(row0 + srow) * K + kq8;
    const __bf16* Ap1 = Ap0 + (long)16 * K;
    int c0i = col0 + srow, c1i = col0 + srow + 16;
    if (c0i > N - 1) c0i = N - 1;
    if (c1i > N - 1) c1i = N - 1;
    const __bf16* Bp0 = Bt + (long)c0i * K + kq8;
    const __bf16* Bp1 = Bt + (long)c1i * K + kq8;
    __bf16* AsW = As + (wid << 10);
    __bf16* BsW = Bs + (wid << 10);

    f32x4 acc[4][4];
#pragma unroll
    for (int i = 0; i < 4; ++i)
#pragma unroll
        for (int j = 0; j < 4; ++j) acc[i][j] = (f32x4){0.f, 0.f, 0.f, 0.f};

    for (int k0 = 0; k0 < K; k0 += 32) {
        glds16(Ap0 + k0, AsW);
        glds16(Ap1 + k0, AsW + 512);
        glds16(Bp0 + k0, BsW);
        glds16(Bp1 + k0, BsW + 512);
        __syncthreads();
        bf16x8 af[4], bfr[4];
        const __bf16* Ar = As + (wm + lrow) * 32 + lkp * 8;
        const __bf16* Br = Bs + (wn + lrow) * 32 + lkp * 8;
#pragma unroll
        for (int i = 0; i < 4; ++i) af[i] = *(const bf16x8*)(Ar + i * 512);
#pragma unroll
        for (int j = 0; j < 4; ++j) bfr[j] = *(const bf16x8*)(Br + j * 512);
#pragma unroll
        for (int i = 0; i < 4; ++i)
#pragma unroll
            for (int j = 0; j < 4; ++j)
                acc[i][j] = __builtin_amdgcn_mfma_f32_16x16x32_bf16(af[i], bfr[j], acc[i][j], 0, 0, 0);
        __syncthreads();
    }

    float* oF = outF ? outF + (long)z * sC : nullptr;
    __bf16* oB = outB ? outB + (long)z * sC : nullptr;
    const float* resp = RES ? res + (long)z * sC : nullptr;
#pragma unroll
    for (int i = 0; i < 4; ++i) {
#pragma unroll
        for (int r = 0; r < 4; ++r) {
            const int gr = row0 + wm + i * 16 + lkp * 4 + r;
#pragma unroll
            for (int j = 0; j < 4; ++j) {
                const int gc = col0 + wn + j * 16 + lrow;
                if (gc >= N) continue;
                float v = acc[i][j][r];
                if (BIAS_MODE == 1) v += bias[gc];
                if (BIAS_MODE == 2) v += bias[gr];
                if (RES) v = (v + resp[(long)gr * N + gc]) * SQH;
                if (ACT == 1) v = fmaxf(v, 0.f);
                if (OUT_MODE == 0 || OUT_MODE == 2) oF[(long)gr * N + gc] = v;
                if (OUT_MODE == 1 || OUT_MODE == 2) oB[(long)gr * N + gc] = (__bf16)v;
            }
        }
    }
}

// ---------------- fused causal dilated conv + GLU + residual ----------------
// Block computes y cols [c0,c0+128) (a-half) and [c0+256,c0+384) (g-half),
// then epilogue: v = (h_in + a*sigmoid(g))*SQH -> hc_f, hc_b, hq_b(+peq).
__global__ __launch_bounds__(256) void conv_glu(
    const __bf16* __restrict__ hbf, const float* __restrict__ hin,
    const __bf16* __restrict__ Wt, const float* __restrict__ bias,
    const float* __restrict__ peq,
    float* __restrict__ hc_f, __bf16* __restrict__ hc_b, __bf16* __restrict__ hq_b,
    int dil, const __bf16* __restrict__ zp)
{
    __shared__ __align__(16) __bf16 As[4096];
    __shared__ __align__(16) __bf16 Ba[4096];
    __shared__ __align__(16) __bf16 Bg[4096];
    const int gx = gridDim.x;
    int lin = blockIdx.y * gx + blockIdx.x;
    lin = xcd_swz(lin, gx * gridDim.y);
    const int bx = lin % gx, by = lin / gx;
    const int row0 = by << 7, col0 = bx << 7;   // col0 in [0,256)
    const int tid = threadIdx.x, wid = tid >> 6, lane = tid & 63;
    const int lrow = lane & 15, lkp = lane >> 4;
    const int wm = (wid >> 1) << 6, wn = (wid & 1) << 6;
    const int srow = (wid << 5) + (lane >> 2);
    const int kq8 = (lane & 3) << 3;
    const int grow = row0 + srow;
    const int t0 = (row0 & 1023) + srow;
    const __bf16* Ba0 = Wt + (long)(col0 + srow) * 1280 + kq8;
    const __bf16* Ba1 = Ba0 + (long)16 * 1280;
    const __bf16* Bg0 = Wt + (long)(col0 + 256 + srow) * 1280 + kq8;
    const __bf16* Bg1 = Bg0 + (long)16 * 1280;
    __bf16* AsW = As + (wid << 10);
    __bf16* BaW = Ba + (wid << 10);
    __bf16* BgW = Bg + (wid << 10);

    f32x4 aca[4][4], acg[4][4];
#pragma unroll
    for (int i = 0; i < 4; ++i)
#pragma unroll
        for (int j = 0; j < 4; ++j) {
            aca[i][j] = (f32x4){0.f, 0.f, 0.f, 0.f};
            acg[i][j] = (f32x4){0.f, 0.f, 0.f, 0.f};
        }

    for (int k0 = 0; k0 < 1280; k0 += 32) {
        const int tap = k0 >> 8;
        const int off = (4 - tap) * dil;
        const int kc = (k0 & 255) + kq8;
        const __bf16* a0 = (t0 >= off) ? hbf + (long)(grow - off) * 256 + kc : zp;
        const __bf16* a1 = (t0 + 16 >= off) ? hbf + (long)(grow + 16 - off) * 256 + kc : zp;
        glds16(a0, AsW);
        glds16(a1, AsW + 512);
        glds16(Ba0 + k0, BaW);
        glds16(Ba1 + k0, BaW + 512);
        glds16(Bg0 + k0, BgW);
        glds16(Bg1 + k0, BgW + 512);
        __syncthreads();
        bf16x8 af[4], ba[4], bg[4];
        const __bf16* Ar = As + (wm + lrow) * 32 + lkp * 8;
        const __bf16* Bar = Ba + (wn + lrow) * 32 + lkp * 8;
        const __bf16* Bgr = Bg + (wn + lrow) * 32 + lkp * 8;
#pragma unroll
        for (int i = 0; i < 4; ++i) af[i] = *(const bf16x8*)(Ar + i * 512);
#pragma unroll
        for (int j = 0; j < 4; ++j) { ba[j] = *(const bf16x8*)(Bar + j * 512); bg[j] = *(const bf16x8*)(Bgr + j * 512); }
#pragma unroll
        for (int i = 0; i < 4; ++i)
#pragma unroll
            for (int j = 0; j < 4; ++j) {
                aca[i][j] = __builtin_amdgcn_mfma_f32_16x16x32_bf16(af[i], ba[j], aca[i][j], 0, 0, 0);
                acg[i][j] = __builtin_amdgcn_mfma_f32_16x16x32_bf16(af[i], bg[j], acg[i][j], 0, 0, 0);
            }
        __syncthreads();
    }
#pragma unroll
    for (int i = 0; i < 4; ++i) {
#pragma unroll
        for (int r = 0; r < 4; ++r) {
            const int gr = row0 + wm + i * 16 + lkp * 4 + r;
            const long rb = (long)gr * 256;
            const long pb = (long)(gr & 1023) * 256;
#pragma unroll
            for (int j = 0; j < 4; ++j) {
                const int ca = col0 + wn + j * 16 + lrow;
                float a = aca[i][j][r] + bias[ca];
                float g = acg[i][j][r] + bias[ca + 256];
                float v = (hin[rb + ca] + a / (1.f + expf(-g))) * SQH;
                hc_f[rb + ca] = v;
                hc_b[rb + ca] = (__bf16)v;
                hq_b[rb + ca] = (__bf16)(v + peq[pb + ca]);
            }
        }
    }
}

// ---------------- fused scores + softmax ----------------
// Per block (512 thr, 8 waves 2x4): S[128 x 512] = Q_tile @ K_z^T (f32),
// row softmax (scaled by rsqrt(512)), write P bf16 to aw.
__global__ __launch_bounds__(512) void scores_sm(
    const __bf16* __restrict__ Q, const __bf16* __restrict__ Kb,
    __bf16* __restrict__ aw)
{
    __shared__ __align__(16) __bf16 As[128 * 32];
    __shared__ __align__(16) __bf16 Bs[512 * 32];
    __shared__ float redM[4][128];
    __shared__ float redS[4][128];
    int lin = xcd_swz(blockIdx.x, gridDim.x);
    const int rt = lin & 7, z = lin >> 3;
    const int row0 = rt << 7;
    const __bf16* Az = Q + (long)z * 1024 * 256;
    const __bf16* Bz = Kb + (long)z * 512 * 256;
    __bf16* awz = aw + (long)z * 1024 * 512;
    const int tid = threadIdx.x, wid = tid >> 6, lane = tid & 63;
    const int lrow = lane & 15, lkp = lane >> 4;
    const int wr = wid >> 2, wc = wid & 3;
    const int sr = lane >> 2;               // 0..15 staging row within 16
    const int kq8 = (lane & 3) << 3;

    f32x4 acc[4][8];
#pragma unroll
    for (int i = 0; i < 4; ++i)
#pragma unroll
        for (int j = 0; j < 8; ++j) acc[i][j] = (f32x4){0.f, 0.f, 0.f, 0.f};

    for (int k0 = 0; k0 < 256; k0 += 32) {
        // A: 128 rows, wave w stages rows [16w,16w+16)
        glds16(Az + (long)(row0 + (wid << 4) + sr) * 256 + k0 + kq8, As + (wid << 9));
        // B: 512 rows, wave w call c stages rows [(c*8+w)*16, +16)
#pragma unroll
        for (int c = 0; c < 4; ++c) {
            const int R = ((c << 3) + wid) << 4;
            glds16(Bz + (long)(R + sr) * 256 + k0 + kq8, Bs + (R << 5));
        }
        __syncthreads();
        bf16x8 af[4], bfr[8];
        const __bf16* Ar = As + ((wr << 6) + lrow) * 32 + lkp * 8;
        const __bf16* Br = Bs + ((wc << 7) + lrow) * 32 + lkp * 8;
#pragma unroll
        for (int i = 0; i < 4; ++i) af[i] = *(const bf16x8*)(Ar + i * 512);
#pragma unroll
        for (int j = 0; j < 8; ++j) bfr[j] = *(const bf16x8*)(Br + j * 512);
#pragma unroll
        for (int i = 0; i < 4; ++i)
#pragma unroll
            for (int j = 0; j < 8; ++j)
                acc[i][j] = __builtin_amdgcn_mfma_f32_16x16x32_bf16(af[i], bfr[j], acc[i][j], 0, 0, 0);
        __syncthreads();
    }

    // ---- row max (wave-local then cross-wave) ----
    float mx[4][4];
#pragma unroll
    for (int i = 0; i < 4; ++i)
#pragma unroll
        for (int r = 0; r < 4; ++r) {
            float m = acc[i][0][r];
#pragma unroll
            for (int j = 1; j < 8; ++j) m = fmaxf(m, acc[i][j][r]);
#pragma unroll
            for (int s = 1; s < 16; s <<= 1) m = fmaxf(m, __shfl_xor(m, s));
            mx[i][r] = m;
        }
    if (lrow == 0) {
#pragma unroll
        for (int i = 0; i < 4; ++i)
#pragma unroll
            for (int r = 0; r < 4; ++r)
                redM[wc][(wr << 6) + i * 16 + (lkp << 2) + r] = mx[i][r];
    }
    __syncthreads();
    float sm[4][4];
#pragma unroll
    for (int i = 0; i < 4; ++i)
#pragma unroll
        for (int r = 0; r < 4; ++r) {
            const int row = (wr << 6) + i * 16 + (lkp << 2) + r;
            float m = fmaxf(fmaxf(redM[0][row], redM[1][row]), fmaxf(redM[2][row], redM[3][row]));
            float s = 0.f;
#pragma unroll
            for (int j = 0; j < 8; ++j) {
                float p = expf(acc[i][j][r] - m);
                acc[i][j][r] = p;
                s += p;
            }
#pragma unroll
            for (int sft = 1; sft < 16; sft <<= 1) s += __shfl_xor(s, sft);
            sm[i][r] = s;
        }
    if (lrow == 0) {
#pragma unroll
        for (int i = 0; i < 4; ++i)
#pragma unroll
            for (int r = 0; r < 4; ++r)
                redS[wc][(wr << 6) + i * 16 + (lkp << 2) + r] = sm[i][r];
    }
    __syncthreads();
#pragma unroll
    for (int i = 0; i < 4; ++i)
#pragma unroll
        for (int r = 0; r < 4; ++r) {
            const int row = (wr << 6) + i * 16 + (lkp << 2) + r;
            float S = redS[0][row] + redS[1][row] + redS[2][row] + redS[3][row];
            float sc = 0.04419417382415922f / S;
            __bf16* op = awz + (long)(row0 + row) * 512 + (wc << 7) + lrow;
#pragma unroll
            for (int j = 0; j < 8; ++j)
                op[j * 16] = (__bf16)(acc[i][j][r] * sc);
        }
}

// ---------------- done head ----------------
__global__ __launch_bounds__(256) void done_kernel(const float* __restrict__ h,
                                                   const float* __restrict__ w,
                                                   const float* __restrict__ b,
                                                   float* __restrict__ out) {
    int row = blockIdx.x * 4 + (threadIdx.x >> 6);
    int lane = threadIdx.x & 63;
    float4 hv = *(const float4*)(h + (long)row * 256 + lane * 4);
    float4 w0 = *(const float4*)(w + lane * 8);
    float4 w1 = *(const float4*)(w + lane * 8 + 4);
    float d0 = hv.x * w0.x + hv.y * w0.z + hv.z * w1.x + hv.w * w1.z;
    float d1 = hv.x * w0.y + hv.y * w0.w + hv.z * w1.y + hv.w * w1.w;
#pragma unroll
    for (int s = 32; s; s >>= 1) { d0 += __shfl_xor(d0, s); d1 += __shfl_xor(d1, s); }
    if (lane == 0) {
        out[(long)row * 2 + 0] = 1.f / (1.f + expf(-(d0 + b[0])));
        out[(long)row * 2 + 1] = 1.f / (1.f + expf(-(d1 + b[1])));
    }
}

// ---------------- launch ----------------
extern "C" void kernel_launch(void* const* d_in, const int* in_sizes, int n_in,
                              void* d_out, int out_size, void* d_ws, size_t ws_size,
                              hipStream_t stream) {
    const float* inputs  = (const float*)d_in[0];
    const float* keys    = (const float*)d_in[1];
    const float* values  = (const float*)d_in[2];
    const float* w_first = (const float*)d_in[3];
    const float* b_first = (const float*)d_in[4];
    const float* fc_w    = (const float*)d_in[5];
    const float* fc_b    = (const float*)d_in[6];
    const float* conv_w  = (const float*)d_in[7];
    const float* conv_b  = (const float*)d_in[8];
    const float* w1 = (const float*)d_in[9];  const float* b1 = (const float*)d_in[10];
    const float* w2 = (const float*)d_in[11]; const float* b2 = (const float*)d_in[12];
    const float* w3 = (const float*)d_in[13]; const float* b3 = (const float*)d_in[14];
    const float* wo = (const float*)d_in[15]; const float* bo = (const float*)d_in[16];
    const float* w_done = (const float*)d_in[17]; const float* b_done = (const float*)d_in[18];
    const float* w_mel  = (const float*)d_in[19]; const float* b_mel  = (const float*)d_in[20];
    float* out = (float*)d_out;
    float* ws  = (float*)d_ws;

    // ---- f32 region ----
    float* peq  = ws;                 // 262144
    float* pek  = peq + 262144;       // 131072
    float* zp   = pek + 131072;       // 64
    float* h_f  = zp + 64;            // 8388608   (layer input / residual-out master)
    float* hc_f = h_f + 8388608;      // 8388608   (conv-block output master)
    // ---- bf16 region ----
    __bf16* h_b   = (__bf16*)(hc_f + 8388608); // 8388608
    __bf16* hc_b  = h_b   + 8388608;           // 8388608
    __bf16* hq_b  = hc_b  + 8388608;           // 8388608
    __bf16* q_bf  = hq_b  + 8388608;           // 8388608  (also ctx after scores)
    __bf16* k_bf  = q_bf  + 8388608;           // 4194304
    __bf16* kpe_bf= k_bf  + 4194304;           // 4194304
    __bf16* val_bf= kpe_bf+ 4194304;           // 4194304
    __bf16* vT_bf = val_bf+ 4194304;           // 4194304
    __bf16* awb   = vT_bf + 4194304;           // 16777216 (also in_bf prologue scratch)
    __bf16* wfT   = awb   + 16777216;          // 81920
    __bf16* fcT   = wfT   + 81920;             // 196608
    __bf16* convT = fcT   + 196608;            // 2621440
    __bf16* w1T   = convT + 2621440;           // 262144
    __bf16* w2T   = w1T   + 262144;            // 262144
    __bf16* w3T   = w2T   + 262144;            // 262144
    __bf16* woT   = w3T   + 262144;            // 262144
    __bf16* wmT   = woT   + 262144;            // 81920
    __bf16* in_bf = awb;                       // alias (prologue only)
    __bf16* ctx_bf = q_bf;                     // alias (q dead after scores)

    dim3 blk(256);

    pos_enc_kernel<<<1024, 256, 0, stream>>>(peq, 1024, 1.0f);
    pos_enc_kernel<<<512, 256, 0, stream>>>(pek, 512, 2.0f);
    zero_init<<<1, 64, 0, stream>>>(zp);

    cvt_bf<<<5120, 256, 0, stream>>>(inputs, in_bf, 1310720);
    cvt_bf<<<2048, 256, 0, stream>>>(values, val_bf, 524288);
    kpe_kernel<<<2048, 256, 0, stream>>>(keys, pek, kpe_bf);

    transpose_k<<<dim3(8, 10, 1), blk, 0, stream>>>(w_first, wfT, 320, 256, 0, 0);
    transpose_k<<<dim3(8, 8, 3), blk, 0, stream>>>(fc_w, fcT, 256, 256, 65536, 65536);
    transpose_k<<<dim3(16, 40, 4), blk, 0, stream>>>(conv_w, convT, 1280, 512, 655360, 655360);
    transpose_k<<<dim3(8, 8, 4), blk, 0, stream>>>(w1, w1T, 256, 256, 65536, 65536);
    transpose_k<<<dim3(8, 8, 4), blk, 0, stream>>>(w2, w2T, 256, 256, 65536, 65536);
    transpose_k<<<dim3(8, 8, 4), blk, 0, stream>>>(w3, w3T, 256, 256, 65536, 65536);
    transpose_k<<<dim3(8, 8, 4), blk, 0, stream>>>(wo, woT, 256, 256, 65536, 65536);
    transpose_k<<<dim3(10, 8, 1), blk, 0, stream>>>(w_mel, wmT, 256, 320, 0, 0);

    // FC chain: in_bf -> h_b chain -> (h_f, h_b)
    gemm_bf<1, 1, 1, 0><<<dim3(2, 256, 1), blk, 0, stream>>>(
        in_bf, wfT, b_first, nullptr, nullptr, h_b, 32768, 256, 320, 0, 0, 0);
    gemm_bf<1, 1, 1, 0><<<dim3(2, 256, 1), blk, 0, stream>>>(
        h_b, fcT + 0 * 65536, fc_b + 0 * 256, nullptr, nullptr, hq_b, 32768, 256, 256, 0, 0, 0);
    gemm_bf<1, 1, 1, 0><<<dim3(2, 256, 1), blk, 0, stream>>>(
        hq_b, fcT + 1 * 65536, fc_b + 1 * 256, nullptr, nullptr, hc_b, 32768, 256, 256, 0, 0, 0);
    gemm_bf<1, 1, 2, 0><<<dim3(2, 256, 1), blk, 0, stream>>>(
        hc_b, fcT + 2 * 65536, fc_b + 2 * 256, nullptr, h_f, h_b, 32768, 256, 256, 0, 0, 0);

    for (int l = 0; l < 4; ++l) {
        int dil = 1 << l;
        // conv + GLU + residual: (h_b, h_f) -> (hc_f, hc_b, hq_b)
        conv_glu<<<dim3(2, 256, 1), blk, 0, stream>>>(
            h_b, h_f, convT + (long)l * 655360, conv_b + l * 512, peq,
            hc_f, hc_b, hq_b, dil, (const __bf16*)zp);
        // q = (hc + peq) @ w2 + b2 -> bf16
        gemm_bf<1, 0, 1, 0><<<dim3(2, 256, 1), blk, 0, stream>>>(
            hq_b, w2T + (long)l * 65536, b2 + l * 256, nullptr, nullptr, q_bf, 32768, 256, 256, 0, 0, 0);
        // k = (keys+pek) @ w1 + b1 -> bf16
        gemm_bf<1, 0, 1, 0><<<dim3(2, 128, 1), blk, 0, stream>>>(
            kpe_bf, w1T + (long)l * 65536, b1 + l * 256, nullptr, nullptr, k_bf, 16384, 256, 256, 0, 0, 0);
        // vT_z = w3T @ values_z^T + b3(row) -> bf16 [256][512]
        gemm_bf<2, 0, 1, 0><<<dim3(4, 2, 32), blk, 0, stream>>>(
            w3T + (long)l * 65536, val_bf, b3 + l * 256, nullptr, nullptr, vT_bf,
            256, 512, 256, 0, 512 * 256, 256 * 512);
        // fused scores + softmax -> P bf16
        scores_sm<<<256, 512, 0, stream>>>(q_bf, k_bf, awb);
        // ctx = P @ v -> bf16 (ctx aliases q_bf)
        gemm_bf<0, 0, 1, 0><<<dim3(2, 8, 32), blk, 0, stream>>>(
            awb, vT_bf, nullptr, nullptr, nullptr, ctx_bf,
            1024, 256, 512, 1024 * 512, 256 * 512, 1024 * 256);
        // h = (ctx @ wo + bo + hc) * SQH -> (h_f, h_b)
        gemm_bf<1, 0, 2, 1><<<dim3(2, 256, 1), blk, 0, stream>>>(
            ctx_bf, woT + (long)l * 65536, bo + l * 256, hc_f, h_f, h_b, 32768, 256, 256, 0, 0, 0);
    }

    gemm_bf<1, 0, 0, 0><<<dim3(3, 256, 1), blk, 0, stream>>>(
        h_b, wmT, b_mel, nullptr, out, nullptr, 32768, 320, 256, 0, 0, 0);
    done_kernel<<<8192, 256, 0, stream>>>(h_f, w_done, b_done, out + 10485760);
    hipMemcpyAsync(out + 10551296, h_f, (size_t)8388608 * 4, hipMemcpyDeviceToDevice, stream);
}

// Round 6
// 1236.088 us; speedup vs baseline: 1.0812x; 1.0812x over previous
//
#include <hip/hip_runtime.h>
#include <hip/hip_bf16.h>
#include <math.h>

#define SQH 0.70710678118654752440f

typedef __bf16 bf16x8 __attribute__((ext_vector_type(8)));
typedef float f32x4 __attribute__((ext_vector_type(4)));

__device__ __forceinline__ void glds16(const void* g, void* l) {
    __builtin_amdgcn_global_load_lds((const __attribute__((address_space(1))) void*)g,
                                     (__attribute__((address_space(3))) void*)l, 16, 0, 0);
}
__device__ __forceinline__ void wait_vm0_barrier() {
    asm volatile("s_waitcnt vmcnt(0)" ::: "memory");
    __builtin_amdgcn_s_barrier();
}

// bijective XCD swizzle (requires n % 8 == 0): contiguous logical chunk per XCD
__device__ __forceinline__ int xcd_swz(int lin, int n) {
    if (n & 7) return lin;
    return (lin & 7) * (n >> 3) + (lin >> 3);
}

// ---------------- positional encoding table ----------------
__global__ void pos_enc_kernel(float* __restrict__ pe, int T, float rate) {
    int idx = blockIdx.x * blockDim.x + threadIdx.x;
    if (idx >= T * 256) return;
    int t = idx >> 8;
    int k = idx & 255;
    float e = 2.0f * (float)(k >> 1) / 256.0f;
    float pw = powf(10000.0f, e);
    float ang = (float)t * ((float)t * rate / pw);
    pe[idx] = ((k & 1) == 0) ? sinf(ang) : cosf(ang);
}

__global__ void zero_init(float* z) { z[threadIdx.x] = 0.f; }

// ---------------- f32 -> bf16 convert (groups of 8) ----------------
__global__ __launch_bounds__(256) void cvt_bf(const float* __restrict__ src,
                                              __bf16* __restrict__ dst, long n8) {
    long i = (long)blockIdx.x * 256 + threadIdx.x;
    if (i >= n8) return;
    const float* s = src + i * 8;
    float4 a = *(const float4*)s, b = *(const float4*)(s + 4);
    bf16x8 o;
    o[0] = (__bf16)a.x; o[1] = (__bf16)a.y; o[2] = (__bf16)a.z; o[3] = (__bf16)a.w;
    o[4] = (__bf16)b.x; o[5] = (__bf16)b.y; o[6] = (__bf16)b.z; o[7] = (__bf16)b.w;
    *(bf16x8*)(dst + i * 8) = o;
}

// ---------------- keys + pek -> bf16 ----------------
__global__ __launch_bounds__(256) void kpe_kernel(const float* __restrict__ keys,
                                                  const float* __restrict__ pek,
                                                  __bf16* __restrict__ dst) {
    long i = (long)blockIdx.x * 256 + threadIdx.x;
    long row = i >> 5; int c8 = (int)(i & 31) << 3;
    const float* kp = keys + row * 256 + c8;
    const float* pp = pek + (row & 511) * 256 + c8;
    float4 a = *(const float4*)kp, b = *(const float4*)(kp + 4);
    float4 p = *(const float4*)pp, q = *(const float4*)(pp + 4);
    bf16x8 o;
    o[0] = (__bf16)(a.x + p.x); o[1] = (__bf16)(a.y + p.y);
    o[2] = (__bf16)(a.z + p.z); o[3] = (__bf16)(a.w + p.w);
    o[4] = (__bf16)(b.x + q.x); o[5] = (__bf16)(b.y + q.y);
    o[6] = (__bf16)(b.z + q.z); o[7] = (__bf16)(b.w + q.w);
    *(bf16x8*)(dst + i * 8) = o;
}

// ---------------- weight transpose: src[R][C] f32 -> dst[C][R] bf16 ----------------
__global__ __launch_bounds__(256) void transpose_k(const float* __restrict__ src,
                                                   __bf16* __restrict__ dst,
                                                   int R, int Cc, long sS, long sD) {
    __shared__ float tile[32][33];
    src += (long)blockIdx.z * sS;
    dst += (long)blockIdx.z * sD;
    int c0 = blockIdx.x * 32, r0 = blockIdx.y * 32;
    int tx = threadIdx.x & 31, ty = threadIdx.x >> 5;
#pragma unroll
    for (int p = 0; p < 4; ++p)
        tile[ty + 8 * p][tx] = src[(long)(r0 + ty + 8 * p) * Cc + c0 + tx];
    __syncthreads();
#pragma unroll
    for (int p = 0; p < 4; ++p)
        dst[(long)(c0 + ty + 8 * p) * R + r0 + tx] = (__bf16)tile[tx][ty + 8 * p];
}

// ---------------- universal bf16 MFMA GEMM (prefetched dbuf LDS) ----------------
// C = epi(A[M,K] @ Bt[N,K]^T + bias). BIAS_MODE: 0 none, 1 col, 2 row.
// ACT: 0 none, 1 relu. OUT_MODE: 0 f32, 1 bf16, 2 both. RES: 1 -> v=(v+res)*SQH.
template<int BIAS_MODE, int ACT, int OUT_MODE, int RES>
__global__ __launch_bounds__(256) void gemm_bf(
    const __bf16* __restrict__ A, const __bf16* __restrict__ Bt,
    const float* __restrict__ bias, const float* __restrict__ res,
    float* __restrict__ outF, __bf16* __restrict__ outB,
    int M, int N, int K, long sA, long sB, long sC)
{
    __shared__ __align__(16) __bf16 As[2][4096];
    __shared__ __align__(16) __bf16 Bs[2][4096];
    const int gx = gridDim.x, gy = gridDim.y;
    int lin = (blockIdx.z * gy + blockIdx.y) * gx + blockIdx.x;
    lin = xcd_swz(lin, gx * gy * gridDim.z);
    const int bx = lin % gx, by = (lin / gx) % gy, z = lin / (gx * gy);
    A += (long)z * sA;
    Bt += (long)z * sB;
    const int row0 = by << 7, col0 = bx << 7;
    const int tid = threadIdx.x, wid = tid >> 6, lane = tid & 63;
    const int lrow = lane & 15, lkp = lane >> 4;
    const int wm = (wid >> 1) << 6, wn = (wid & 1) << 6;
    const int srow = (wid << 5) + (lane >> 2);
    const int kq8 = (lane & 3) << 3;
    const __bf16* Ap0 = A + (long)(row0 + srow) * K + kq8;
    const __bf16* Ap1 = Ap0 + (long)16 * K;
    int c0i = col0 + srow, c1i = col0 + srow + 16;
    if (c0i > N - 1) c0i = N - 1;
    if (c1i > N - 1) c1i = N - 1;
    const __bf16* Bp0 = Bt + (long)c0i * K + kq8;
    const __bf16* Bp1 = Bt + (long)c1i * K + kq8;

    auto stage = [&](int b, int k0) {
        __bf16* A_ = As[b] + (wid << 10);
        __bf16* B_ = Bs[b] + (wid << 10);
        glds16(Ap0 + k0, A_);
        glds16(Ap1 + k0, A_ + 512);
        glds16(Bp0 + k0, B_);
        glds16(Bp1 + k0, B_ + 512);
    };

    f32x4 acc[4][4];
#pragma unroll
    for (int i = 0; i < 4; ++i)
#pragma unroll
        for (int j = 0; j < 4; ++j) acc[i][j] = (f32x4){0.f, 0.f, 0.f, 0.f};

    const int nk = K >> 5;
    stage(0, 0);
    wait_vm0_barrier();
    int cur = 0;
    for (int t = 0; t < nk; ++t) {
        if (t + 1 < nk) stage(cur ^ 1, (t + 1) << 5);
        bf16x8 af[4], bfr[4];
        const __bf16* Ar = As[cur] + (wm + lrow) * 32 + lkp * 8;
        const __bf16* Br = Bs[cur] + (wn + lrow) * 32 + lkp * 8;
#pragma unroll
        for (int i = 0; i < 4; ++i) af[i] = *(const bf16x8*)(Ar + i * 512);
#pragma unroll
        for (int j = 0; j < 4; ++j) bfr[j] = *(const bf16x8*)(Br + j * 512);
#pragma unroll
        for (int i = 0; i < 4; ++i)
#pragma unroll
            for (int j = 0; j < 4; ++j)
                acc[i][j] = __builtin_amdgcn_mfma_f32_16x16x32_bf16(af[i], bfr[j], acc[i][j], 0, 0, 0);
        wait_vm0_barrier();
        cur ^= 1;
    }

    float* oF = outF ? outF + (long)z * sC : nullptr;
    __bf16* oB = outB ? outB + (long)z * sC : nullptr;
    const float* resp = RES ? res + (long)z * sC : nullptr;
#pragma unroll
    for (int i = 0; i < 4; ++i) {
#pragma unroll
        for (int r = 0; r < 4; ++r) {
            const int gr = row0 + wm + i * 16 + lkp * 4 + r;
#pragma unroll
            for (int j = 0; j < 4; ++j) {
                const int gc = col0 + wn + j * 16 + lrow;
                if (gc >= N) continue;
                float v = acc[i][j][r];
                if (BIAS_MODE == 1) v += bias[gc];
                if (BIAS_MODE == 2) v += bias[gr];
                if (RES) v = (v + resp[(long)gr * N + gc]) * SQH;
                if (ACT == 1) v = fmaxf(v, 0.f);
                if (OUT_MODE == 0 || OUT_MODE == 2) oF[(long)gr * N + gc] = v;
                if (OUT_MODE == 1 || OUT_MODE == 2) oB[(long)gr * N + gc] = (__bf16)v;
            }
        }
    }
}

// ---------------- fused causal dilated conv + GLU + residual (prefetched dbuf) -----
// Block: 128 rows x 64 col-pairs (a: cols [c0,c0+64), g: cols [c0+256,+64)).
// Epilogue: v = (h_in + a*sigmoid(g))*SQH -> hc_f, hc_b, hq_b(+peq).
__global__ __launch_bounds__(256) void conv_glu(
    const __bf16* __restrict__ hbf, const float* __restrict__ hin,
    const __bf16* __restrict__ Wt, const float* __restrict__ bias,
    const float* __restrict__ peq,
    float* __restrict__ hc_f, __bf16* __restrict__ hc_b, __bf16* __restrict__ hq_b,
    int dil, const __bf16* __restrict__ zp)
{
    __shared__ __align__(16) __bf16 As[2][4096];
    __shared__ __align__(16) __bf16 Bas[2][2048];
    __shared__ __align__(16) __bf16 Bgs[2][2048];
    const int gx = gridDim.x;
    int lin = blockIdx.y * gx + blockIdx.x;
    lin = xcd_swz(lin, gx * gridDim.y);
    const int bx = lin % gx, by = lin / gx;
    const int row0 = by << 7, col0 = bx << 6;   // col0 in [0,256), 64-pair tiles
    const int tid = threadIdx.x, wid = tid >> 6, lane = tid & 63;
    const int lrow = lane & 15, lkp = lane >> 4;
    const int wr = wid >> 1, wc = wid & 1;
    const int sA = (wid << 5) + (lane >> 2);    // A staging row 0..127 (16 per wave call)
    const int kq8 = (lane & 3) << 3;
    const int grow = row0 + sA;
    const int t0 = (row0 & 1023) + sA;
    const int cB = col0 + (wid << 4) + (lane >> 2);  // B staging col (16 per wave)
    const __bf16* Ba0 = Wt + (long)cB * 1280 + kq8;
    const __bf16* Bg0 = Wt + (long)(cB + 256) * 1280 + kq8;

    auto stage = [&](int b, int k0) {
        const int tap = k0 >> 8;
        const int off = (4 - tap) * dil;
        const int kc = (k0 & 255) + kq8;
        const __bf16* a0 = (t0 >= off) ? hbf + (long)(grow - off) * 256 + kc : zp;
        const __bf16* a1 = (t0 + 16 >= off) ? hbf + (long)(grow + 16 - off) * 256 + kc : zp;
        __bf16* A_ = As[b] + (wid << 10);
        glds16(a0, A_);
        glds16(a1, A_ + 512);
        glds16(Ba0 + k0, Bas[b] + (wid << 9));
        glds16(Bg0 + k0, Bgs[b] + (wid << 9));
    };

    f32x4 aca[4][2], acg[4][2];
#pragma unroll
    for (int i = 0; i < 4; ++i)
#pragma unroll
        for (int j = 0; j < 2; ++j) {
            aca[i][j] = (f32x4){0.f, 0.f, 0.f, 0.f};
            acg[i][j] = (f32x4){0.f, 0.f, 0.f, 0.f};
        }

    stage(0, 0);
    wait_vm0_barrier();
    int cur = 0;
    for (int t = 0; t < 40; ++t) {
        if (t + 1 < 40) stage(cur ^ 1, (t + 1) << 5);
        bf16x8 af[4], ba[2], bg[2];
        const __bf16* Ar = As[cur] + ((wr << 6) + lrow) * 32 + lkp * 8;
        const __bf16* Bar = Bas[cur] + ((wc << 5) + lrow) * 32 + lkp * 8;
        const __bf16* Bgr = Bgs[cur] + ((wc << 5) + lrow) * 32 + lkp * 8;
#pragma unroll
        for (int i = 0; i < 4; ++i) af[i] = *(const bf16x8*)(Ar + i * 512);
#pragma unroll
        for (int j = 0; j < 2; ++j) { ba[j] = *(const bf16x8*)(Bar + j * 512); bg[j] = *(const bf16x8*)(Bgr + j * 512); }
#pragma unroll
        for (int i = 0; i < 4; ++i)
#pragma unroll
            for (int j = 0; j < 2; ++j) {
                aca[i][j] = __builtin_amdgcn_mfma_f32_16x16x32_bf16(af[i], ba[j], aca[i][j], 0, 0, 0);
                acg[i][j] = __builtin_amdgcn_mfma_f32_16x16x32_bf16(af[i], bg[j], acg[i][j], 0, 0, 0);
            }
        wait_vm0_barrier();
        cur ^= 1;
    }
#pragma unroll
    for (int i = 0; i < 4; ++i) {
#pragma unroll
        for (int r = 0; r < 4; ++r) {
            const int gr = row0 + (wr << 6) + i * 16 + lkp * 4 + r;
            const long rb = (long)gr * 256;
            const long pb = (long)(gr & 1023) * 256;
#pragma unroll
            for (int j = 0; j < 2; ++j) {
                const int ca = col0 + (wc << 5) + j * 16 + lrow;
                float a = aca[i][j][r] + bias[ca];
                float g = acg[i][j][r] + bias[ca + 256];
                float v = (hin[rb + ca] + a / (1.f + expf(-g))) * SQH;
                hc_f[rb + ca] = v;
                hc_b[rb + ca] = (__bf16)v;
                hq_b[rb + ca] = (__bf16)(v + peq[pb + ca]);
            }
        }
    }
}

// ---------------- fused scores + softmax (prefetched dbuf) ----------------
// Per block (512 thr, 8 waves 2x4): S[128 x 512] = Q_tile @ K_z^T (f32),
// row softmax (scaled by rsqrt(512)), write P bf16 to aw.
__global__ __launch_bounds__(512) void scores_sm(
    const __bf16* __restrict__ Q, const __bf16* __restrict__ Kb,
    __bf16* __restrict__ aw)
{
    __shared__ __align__(16) __bf16 As[2][128 * 32];
    __shared__ __align__(16) __bf16 Bs[2][512 * 32];
    __shared__ float redM[4][128];
    __shared__ float redS[4][128];
    int lin = xcd_swz(blockIdx.x, gridDim.x);
    const int rt = lin & 7, z = lin >> 3;
    const int row0 = rt << 7;
    const __bf16* Az = Q + (long)z * 1024 * 256;
    const __bf16* Bz = Kb + (long)z * 512 * 256;
    __bf16* awz = aw + (long)z * 1024 * 512;
    const int tid = threadIdx.x, wid = tid >> 6, lane = tid & 63;
    const int lrow = lane & 15, lkp = lane >> 4;
    const int wr = wid >> 2, wc = wid & 3;
    const int sr = lane >> 2;
    const int kq8 = (lane & 3) << 3;

    auto stage = [&](int b, int k0) {
        glds16(Az + (long)(row0 + (wid << 4) + sr) * 256 + k0 + kq8, As[b] + (wid << 9));
#pragma unroll
        for (int c = 0; c < 4; ++c) {
            const int R = ((c << 3) + wid) << 4;
            glds16(Bz + (long)(R + sr) * 256 + k0 + kq8, Bs[b] + (R << 5));
        }
    };

    f32x4 acc[4][8];
#pragma unroll
    for (int i = 0; i < 4; ++i)
#pragma unroll
        for (int j = 0; j < 8; ++j) acc[i][j] = (f32x4){0.f, 0.f, 0.f, 0.f};

    stage(0, 0);
    wait_vm0_barrier();
    int cur = 0;
    for (int t = 0; t < 8; ++t) {
        if (t + 1 < 8) stage(cur ^ 1, (t + 1) << 5);
        bf16x8 af[4], bfr[8];
        const __bf16* Ar = As[cur] + ((wr << 6) + lrow) * 32 + lkp * 8;
        const __bf16* Br = Bs[cur] + ((wc << 7) + lrow) * 32 + lkp * 8;
#pragma unroll
        for (int i = 0; i < 4; ++i) af[i] = *(const bf16x8*)(Ar + i * 512);
#pragma unroll
        for (int j = 0; j < 8; ++j) bfr[j] = *(const bf16x8*)(Br + j * 512);
#pragma unroll
        for (int i = 0; i < 4; ++i)
#pragma unroll
            for (int j = 0; j < 8; ++j)
                acc[i][j] = __builtin_amdgcn_mfma_f32_16x16x32_bf16(af[i], bfr[j], acc[i][j], 0, 0, 0);
        wait_vm0_barrier();
        cur ^= 1;
    }

    // ---- row max (wave-local then cross-wave) ----
    float mx[4][4];
#pragma unroll
    for (int i = 0; i < 4; ++i)
#pragma unroll
        for (int r = 0; r < 4; ++r) {
            float m = acc[i][0][r];
#pragma unroll
            for (int j = 1; j < 8; ++j) m = fmaxf(m, acc[i][j][r]);
#pragma unroll
            for (int s = 1; s < 16; s <<= 1) m = fmaxf(m, __shfl_xor(m, s));
            mx[i][r] = m;
        }
    if (lrow == 0) {
#pragma unroll
        for (int i = 0; i < 4; ++i)
#pragma unroll
            for (int r = 0; r < 4; ++r)
                redM[wc][(wr << 6) + i * 16 + (lkp << 2) + r] = mx[i][r];
    }
    __syncthreads();
    float sm[4][4];
#pragma unroll
    for (int i = 0; i < 4; ++i)
#pragma unroll
        for (int r = 0; r < 4; ++r) {
            const int row = (wr << 6) + i * 16 + (lkp << 2) + r;
            float m = fmaxf(fmaxf(redM[0][row], redM[1][row]), fmaxf(redM[2][row], redM[3][row]));
            float s = 0.f;
#pragma unroll
            for (int j = 0; j < 8; ++j) {
                float p = expf(acc[i][j][r] - m);
                acc[i][j][r] = p;
                s += p;
            }
#pragma unroll
            for (int sft = 1; sft < 16; sft <<= 1) s += __shfl_xor(s, sft);
            sm[i][r] = s;
        }
    if (lrow == 0) {
#pragma unroll
        for (int i = 0; i < 4; ++i)
#pragma unroll
            for (int r = 0; r < 4; ++r)
                redS[wc][(wr << 6) + i * 16 + (lkp << 2) + r] = sm[i][r];
    }
    __syncthreads();
#pragma unroll
    for (int i = 0; i < 4; ++i)
#pragma unroll
        for (int r = 0; r < 4; ++r) {
            const int row = (wr << 6) + i * 16 + (lkp << 2) + r;
            float S = redS[0][row] + redS[1][row] + redS[2][row] + redS[3][row];
            float sc = 0.04419417382415922f / S;
            __bf16* op = awz + (long)(row0 + row) * 512 + (wc << 7) + lrow;
#pragma unroll
            for (int j = 0; j < 8; ++j)
                op[j * 16] = (__bf16)(acc[i][j][r] * sc);
        }
}

// ---------------- done head ----------------
__global__ __launch_bounds__(256) void done_kernel(const float* __restrict__ h,
                                                   const float* __restrict__ w,
                                                   const float* __restrict__ b,
                                                   float* __restrict__ out) {
    int row = blockIdx.x * 4 + (threadIdx.x >> 6);
    int lane = threadIdx.x & 63;
    float4 hv = *(const float4*)(h + (long)row * 256 + lane * 4);
    float4 w0 = *(const float4*)(w + lane * 8);
    float4 w1 = *(const float4*)(w + lane * 8 + 4);
    float d0 = hv.x * w0.x + hv.y * w0.z + hv.z * w1.x + hv.w * w1.z;
    float d1 = hv.x * w0.y + hv.y * w0.w + hv.z * w1.y + hv.w * w1.w;
#pragma unroll
    for (int s = 32; s; s >>= 1) { d0 += __shfl_xor(d0, s); d1 += __shfl_xor(d1, s); }
    if (lane == 0) {
        out[(long)row * 2 + 0] = 1.f / (1.f + expf(-(d0 + b[0])));
        out[(long)row * 2 + 1] = 1.f / (1.f + expf(-(d1 + b[1])));
    }
}

// ---------------- launch ----------------
extern "C" void kernel_launch(void* const* d_in, const int* in_sizes, int n_in,
                              void* d_out, int out_size, void* d_ws, size_t ws_size,
                              hipStream_t stream) {
    const float* inputs  = (const float*)d_in[0];
    const float* keys    = (const float*)d_in[1];
    const float* values  = (const float*)d_in[2];
    const float* w_first = (const float*)d_in[3];
    const float* b_first = (const float*)d_in[4];
    const float* fc_w    = (const float*)d_in[5];
    const float* fc_b    = (const float*)d_in[6];
    const float* conv_w  = (const float*)d_in[7];
    const float* conv_b  = (const float*)d_in[8];
    const float* w1 = (const float*)d_in[9];  const float* b1 = (const float*)d_in[10];
    const float* w2 = (const float*)d_in[11]; const float* b2 = (const float*)d_in[12];
    const float* w3 = (const float*)d_in[13]; const float* b3 = (const float*)d_in[14];
    const float* wo = (const float*)d_in[15]; const float* bo = (const float*)d_in[16];
    const float* w_done = (const float*)d_in[17]; const float* b_done = (const float*)d_in[18];
    const float* w_mel  = (const float*)d_in[19]; const float* b_mel  = (const float*)d_in[20];
    float* out = (float*)d_out;
    float* ws  = (float*)d_ws;

    // ---- f32 region ----
    float* peq  = ws;                 // 262144
    float* pek  = peq + 262144;       // 131072
    float* zp   = pek + 131072;       // 64
    float* h_f  = zp + 64;            // 8388608   (layer input / residual-out master)
    float* hc_f = h_f + 8388608;      // 8388608   (conv-block output master)
    // ---- bf16 region ----
    __bf16* h_b   = (__bf16*)(hc_f + 8388608); // 8388608
    __bf16* hc_b  = h_b   + 8388608;           // 8388608
    __bf16* hq_b  = hc_b  + 8388608;           // 8388608
    __bf16* q_bf  = hq_b  + 8388608;           // 8388608  (also ctx after scores)
    __bf16* k_bf  = q_bf  + 8388608;           // 4194304
    __bf16* kpe_bf= k_bf  + 4194304;           // 4194304
    __bf16* val_bf= kpe_bf+ 4194304;           // 4194304
    __bf16* vT_bf = val_bf+ 4194304;           // 4194304
    __bf16* awb   = vT_bf + 4194304;           // 16777216 (also in_bf prologue scratch)
    __bf16* wfT   = awb   + 16777216;          // 81920
    __bf16* fcT   = wfT   + 81920;             // 196608
    __bf16* convT = fcT   + 196608;            // 2621440
    __bf16* w1T   = convT + 2621440;           // 262144
    __bf16* w2T   = w1T   + 262144;            // 262144
    __bf16* w3T   = w2T   + 262144;            // 262144
    __bf16* woT   = w3T   + 262144;            // 262144
    __bf16* wmT   = woT   + 262144;            // 81920
    __bf16* in_bf = awb;                       // alias (prologue only)
    __bf16* ctx_bf = q_bf;                     // alias (q dead after scores)

    dim3 blk(256);

    pos_enc_kernel<<<1024, 256, 0, stream>>>(peq, 1024, 1.0f);
    pos_enc_kernel<<<512, 256, 0, stream>>>(pek, 512, 2.0f);
    zero_init<<<1, 64, 0, stream>>>(zp);

    cvt_bf<<<5120, 256, 0, stream>>>(inputs, in_bf, 1310720);
    cvt_bf<<<2048, 256, 0, stream>>>(values, val_bf, 524288);
    kpe_kernel<<<2048, 256, 0, stream>>>(keys, pek, kpe_bf);

    transpose_k<<<dim3(8, 10, 1), blk, 0, stream>>>(w_first, wfT, 320, 256, 0, 0);
    transpose_k<<<dim3(8, 8, 3), blk, 0, stream>>>(fc_w, fcT, 256, 256, 65536, 65536);
    transpose_k<<<dim3(16, 40, 4), blk, 0, stream>>>(conv_w, convT, 1280, 512, 655360, 655360);
    transpose_k<<<dim3(8, 8, 4), blk, 0, stream>>>(w1, w1T, 256, 256, 65536, 65536);
    transpose_k<<<dim3(8, 8, 4), blk, 0, stream>>>(w2, w2T, 256, 256, 65536, 65536);
    transpose_k<<<dim3(8, 8, 4), blk, 0, stream>>>(w3, w3T, 256, 256, 65536, 65536);
    transpose_k<<<dim3(8, 8, 4), blk, 0, stream>>>(wo, woT, 256, 256, 65536, 65536);
    transpose_k<<<dim3(10, 8, 1), blk, 0, stream>>>(w_mel, wmT, 256, 320, 0, 0);

    // FC chain: in_bf -> h_b chain -> (h_f, h_b)
    gemm_bf<1, 1, 1, 0><<<dim3(2, 256, 1), blk, 0, stream>>>(
        in_bf, wfT, b_first, nullptr, nullptr, h_b, 32768, 256, 320, 0, 0, 0);
    gemm_bf<1, 1, 1, 0><<<dim3(2, 256, 1), blk, 0, stream>>>(
        h_b, fcT + 0 * 65536, fc_b + 0 * 256, nullptr, nullptr, hq_b, 32768, 256, 256, 0, 0, 0);
    gemm_bf<1, 1, 1, 0><<<dim3(2, 256, 1), blk, 0, stream>>>(
        hq_b, fcT + 1 * 65536, fc_b + 1 * 256, nullptr, nullptr, hc_b, 32768, 256, 256, 0, 0, 0);
    gemm_bf<1, 1, 2, 0><<<dim3(2, 256, 1), blk, 0, stream>>>(
        hc_b, fcT + 2 * 65536, fc_b + 2 * 256, nullptr, h_f, h_b, 32768, 256, 256, 0, 0, 0);

    for (int l = 0; l < 4; ++l) {
        int dil = 1 << l;
        // conv + GLU + residual: (h_b, h_f) -> (hc_f, hc_b, hq_b)
        conv_glu<<<dim3(4, 256, 1), blk, 0, stream>>>(
            h_b, h_f, convT + (long)l * 655360, conv_b + l * 512, peq,
            hc_f, hc_b, hq_b, dil, (const __bf16*)zp);
        // q = (hc + peq) @ w2 + b2 -> bf16
        gemm_bf<1, 0, 1, 0><<<dim3(2, 256, 1), blk, 0, stream>>>(
            hq_b, w2T + (long)l * 65536, b2 + l * 256, nullptr, nullptr, q_bf, 32768, 256, 256, 0, 0, 0);
        // k = (keys+pek) @ w1 + b1 -> bf16
        gemm_bf<1, 0, 1, 0><<<dim3(2, 128, 1), blk, 0, stream>>>(
            kpe_bf, w1T + (long)l * 65536, b1 + l * 256, nullptr, nullptr, k_bf, 16384, 256, 256, 0, 0, 0);
        // vT_z = w3T @ values_z^T + b3(row) -> bf16 [256][512]
        gemm_bf<2, 0, 1, 0><<<dim3(4, 2, 32), blk, 0, stream>>>(
            w3T + (long)l * 65536, val_bf, b3 + l * 256, nullptr, nullptr, vT_bf,
            256, 512, 256, 0, 512 * 256, 256 * 512);
        // fused scores + softmax -> P bf16
        scores_sm<<<256, 512, 0, stream>>>(q_bf, k_bf, awb);
        // ctx = P @ v -> bf16 (ctx aliases q_bf)
        gemm_bf<0, 0, 1, 0><<<dim3(2, 8, 32), blk, 0, stream>>>(
            awb, vT_bf, nullptr, nullptr, nullptr, ctx_bf,
            1024, 256, 512, 1024 * 512, 256 * 512, 1024 * 256);
        // h = (ctx @ wo + bo + hc) * SQH -> (h_f, h_b)
        gemm_bf<1, 0, 2, 1><<<dim3(2, 256, 1), blk, 0, stream>>>(
            ctx_bf, woT + (long)l * 65536, bo + l * 256, hc_f, h_f, h_b, 32768, 256, 256, 0, 0, 0);
    }

    gemm_bf<1, 0, 0, 0><<<dim3(3, 256, 1), blk, 0, stream>>>(
        h_b, wmT, b_mel, nullptr, out, nullptr, 32768, 320, 256, 0, 0, 0);
    done_kernel<<<8192, 256, 0, stream>>>(h_f, w_done, b_done, out + 10485760);
    hipMemcpyAsync(out + 10551296, h_f, (size_t)8388608 * 4, hipMemcpyDeviceToDevice, stream);
}